// Round 3
// baseline (415.952 us; speedup 1.0000x reference)
//
#include <hip/hip_runtime.h>

// Problem constants (from reference)
#define BB 4
#define CC 256
#define HH 256
#define WW 256
#define HWV (HH * WW)          // 65536
#define N_BOX 64
#define SS 7
#define NPTS (SS * SS)         // 49
#define NROI (BB * N_BOX)      // 256
#define ROI_SCALE 0.25f

#define CG 32                  // channels per gather block
#define NGRP (CC / CG)         // 8 channel groups -> 2048 blocks
#define ITEMS (CG * NPTS)      // 1568 items per block
#define PPR (4 * NPTS)         // 196 params per roi (per array)

// ---------------------------------------------------------------------------
// Kernel P: per-roi sample-point precompute -> workspace.
// offs[r][k][p] = clamped flat offset y*W+x for corner k of point p
// wts [r][k][p] = bilinear weight * validity
// ---------------------------------------------------------------------------
__global__ __launch_bounds__(64) void precompute_kernel(
    const float* __restrict__ rois,
    int* __restrict__ offs,     // (NROI, 4, 49)
    float* __restrict__ wts)    // (NROI, 4, 49)
{
    const int r = blockIdx.x;
    const int tid = threadIdx.x;
    if (tid >= NPTS) return;

    const float cx = rois[r * 5 + 0] * ROI_SCALE;
    const float cy = rois[r * 5 + 1] * ROI_SCALE;
    const float bw = rois[r * 5 + 2] * ROI_SCALE;
    const float bh = rois[r * 5 + 3] * ROI_SCALE;
    const float th = rois[r * 5 + 4];
    const float ct = cosf(th);
    const float st = sinf(th);

    const int py = tid / SS;
    const int px = tid - py * SS;
    const float lu = (px + 0.5f) / (float)SS - 0.5f;
    const float lv = (py + 0.5f) / (float)SS - 0.5f;
    const float u = lu * bw;
    const float v = lv * bh;
    const float x = cx + u * ct - v * st;
    const float y = cy + u * st + v * ct;

    const float x0f = floorf(x), y0f = floorf(y);
    const float x1f = x0f + 1.0f, y1f = y0f + 1.0f;
    const float wx1 = x - x0f, wx0 = 1.0f - wx1;
    const float wy1 = y - y0f, wy0 = 1.0f - wy1;

    const bool vx0 = (x0f >= 0.0f) && (x0f <= (float)(WW - 1));
    const bool vx1 = (x1f >= 0.0f) && (x1f <= (float)(WW - 1));
    const bool vy0 = (y0f >= 0.0f) && (y0f <= (float)(HH - 1));
    const bool vy1 = (y1f >= 0.0f) && (y1f <= (float)(HH - 1));

    const int x0c = min(max((int)x0f, 0), WW - 1);
    const int x1c = min(max((int)x1f, 0), WW - 1);
    const int y0c = min(max((int)y0f, 0), HH - 1);
    const int y1c = min(max((int)y1f, 0), HH - 1);

    int*   ro = offs + (size_t)r * PPR;
    float* rw = wts  + (size_t)r * PPR;
    ro[0 * NPTS + tid] = y0c * WW + x0c;  rw[0 * NPTS + tid] = (vx0 && vy0) ? wx0 * wy0 : 0.0f;
    ro[1 * NPTS + tid] = y0c * WW + x1c;  rw[1 * NPTS + tid] = (vx1 && vy0) ? wx1 * wy0 : 0.0f;
    ro[2 * NPTS + tid] = y1c * WW + x0c;  rw[2 * NPTS + tid] = (vx0 && vy1) ? wx0 * wy1 : 0.0f;
    ro[3 * NPTS + tid] = y1c * WW + x1c;  rw[3 * NPTS + tid] = (vx1 && vy1) ? wx1 * wy1 : 0.0f;
}

// ---------------------------------------------------------------------------
// Kernel G: gather. Block = (roi, 32-channel group) -> 2048 blocks, 256 thr.
// __launch_bounds__(256, 8): cap VGPR at 64 so 8 waves/SIMD = 32 waves/CU
// (2048 blocks / 256 CU = 8 blocks/CU x 4 waves = full occupancy) — the R1
// kernel at 1024 blocks sat at 16 waves/CU and was latency-bound.
// ---------------------------------------------------------------------------
__global__ __launch_bounds__(256, 8) void gather_kernel(
    const float* __restrict__ feats,   // (B, C, H, W)
    const int* __restrict__ offs,      // (NROI, 4, 49)
    const float* __restrict__ wts,     // (NROI, 4, 49)
    float* __restrict__ out)           // (NROI, C, 7, 7)
{
    __shared__ int   s_off[PPR];
    __shared__ float s_w[PPR];

    const int r   = blockIdx.x;
    const int cg  = blockIdx.y;
    const int b   = r >> 6;
    const int tid = threadIdx.x;

    if (tid < PPR) {
        s_off[tid] = offs[(size_t)r * PPR + tid];
        s_w[tid]   = wts [(size_t)r * PPR + tid];
    }
    __syncthreads();

    const float* plane_base = feats + ((size_t)b * CC + (size_t)cg * CG) * HWV;
    float* ob = out + ((size_t)r * CC + (size_t)cg * CG) * NPTS;

    // 1568 = 6*256 + 32: six full strides, then a 32-thread tail.
    #pragma unroll 3
    for (int it = 0; it < 6; ++it) {
        const int i  = tid + it * 256;
        const int cl = i / NPTS;
        const int p  = i - cl * NPTS;
        const float* plane = plane_base + (size_t)cl * HWV;
        const float v0 = plane[s_off[0 * NPTS + p]];
        const float v1 = plane[s_off[1 * NPTS + p]];
        const float v2 = plane[s_off[2 * NPTS + p]];
        const float v3 = plane[s_off[3 * NPTS + p]];
        ob[i] = s_w[0 * NPTS + p] * v0 + s_w[1 * NPTS + p] * v1
              + s_w[2 * NPTS + p] * v2 + s_w[3 * NPTS + p] * v3;
    }
    if (tid < ITEMS - 6 * 256) {
        const int i  = tid + 6 * 256;
        const int cl = i / NPTS;
        const int p  = i - cl * NPTS;
        const float* plane = plane_base + (size_t)cl * HWV;
        const float v0 = plane[s_off[0 * NPTS + p]];
        const float v1 = plane[s_off[1 * NPTS + p]];
        const float v2 = plane[s_off[2 * NPTS + p]];
        const float v3 = plane[s_off[3 * NPTS + p]];
        ob[i] = s_w[0 * NPTS + p] * v0 + s_w[1 * NPTS + p] * v1
              + s_w[2 * NPTS + p] * v2 + s_w[3 * NPTS + p] * v3;
    }
}

extern "C" void kernel_launch(void* const* d_in, const int* in_sizes, int n_in,
                              void* d_out, int out_size, void* d_ws, size_t ws_size,
                              hipStream_t stream) {
    const float* feats = (const float*)d_in[0];
    const float* rois  = (const float*)d_in[1];
    float* out = (float*)d_out;

    int*   offs = (int*)d_ws;                       // NROI*196 ints
    float* wts  = (float*)((char*)d_ws + (size_t)NROI * PPR * sizeof(int));

    precompute_kernel<<<NROI, 64, 0, stream>>>(rois, offs, wts);

    dim3 g(NROI, NGRP);   // 256 x 8 = 2048 blocks
    gather_kernel<<<g, 256, 0, stream>>>(feats, offs, wts, out);
}

// Round 4
// 408.297 us; speedup vs baseline: 1.0187x; 1.0187x over previous
//
#include <hip/hip_runtime.h>

// Problem constants (from reference)
#define BB 4
#define CC 256
#define HH 256
#define WW 256
#define HWV (HH * WW)          // 65536
#define N_BOX 64
#define SS 7
#define NPTS (SS * SS)         // 49
#define NROI (BB * N_BOX)      // 256
#define ROI_SCALE 0.25f

#define NCAND (NPTS * 4)       // 196 candidate quads per roi
#define CG 32                  // channels per gather block
#define NGRP (CC / CG)         // 8 -> 2048 blocks

// workspace layout (all 16B-aligned segments)
#define WS_WTS_OFF   0                                        // NROI*49 float4
#define WS_SLOT_OFF  (WS_WTS_OFF + NROI * NPTS * 16)          // NROI*49 short4
#define WS_UOFF_OFF  (WS_SLOT_OFF + NROI * NPTS * 8)          // NROI*196 int
#define WS_APK_OFF   (WS_UOFF_OFF + NROI * NCAND * 4)         // NROI*49 int
#define WS_NU_OFF    (WS_APK_OFF + NROI * NPTS * 4)           // NROI int
#define WS_NEED      (WS_NU_OFF + NROI * 4)

// ---------------------------------------------------------------------------
// Kernel P: per-roi precompute. One block per roi.
// Emits: deduplicated list of aligned-float4 quad offsets (y*256 + (x&~3)),
// per-sample 4 slot indices into that list, per-sample x-shifts, 4 weights.
// Shared across all 256 channels of the roi.
// ---------------------------------------------------------------------------
__global__ __launch_bounds__(256) void precompute_kernel(
    const float* __restrict__ rois,
    float4* __restrict__ g_wts,     // (NROI*49)
    short4* __restrict__ g_slots,   // (NROI*49)
    int* __restrict__ g_uoff,       // (NROI*196)
    int* __restrict__ g_apk,        // (NROI*49)
    int* __restrict__ g_nu)         // (NROI)
{
    __shared__ int cand[NCAND];
    __shared__ int lead[NCAND];
    __shared__ int flag[NCAND];
    __shared__ int pre[NCAND];

    const int r = blockIdx.x;
    const int tid = threadIdx.x;

    if (tid < NPTS) {
        const float cx = rois[r * 5 + 0] * ROI_SCALE;
        const float cy = rois[r * 5 + 1] * ROI_SCALE;
        const float bw = rois[r * 5 + 2] * ROI_SCALE;
        const float bh = rois[r * 5 + 3] * ROI_SCALE;
        const float th = rois[r * 5 + 4];
        const float ct = cosf(th);
        const float st = sinf(th);

        const int py = tid / SS;
        const int px = tid - py * SS;
        const float lu = (px + 0.5f) / (float)SS - 0.5f;
        const float lv = (py + 0.5f) / (float)SS - 0.5f;
        const float u = lu * bw;
        const float v = lv * bh;
        const float x = cx + u * ct - v * st;
        const float y = cy + u * st + v * ct;

        const float x0f = floorf(x), y0f = floorf(y);
        const float x1f = x0f + 1.0f, y1f = y0f + 1.0f;
        const float wx1 = x - x0f, wx0 = 1.0f - wx1;
        const float wy1 = y - y0f, wy0 = 1.0f - wy1;

        const bool vx0 = (x0f >= 0.0f) && (x0f <= (float)(WW - 1));
        const bool vx1 = (x1f >= 0.0f) && (x1f <= (float)(WW - 1));
        const bool vy0 = (y0f >= 0.0f) && (y0f <= (float)(HH - 1));
        const bool vy1 = (y1f >= 0.0f) && (y1f <= (float)(HH - 1));

        const int x0c = min(max((int)x0f, 0), WW - 1);
        const int x1c = min(max((int)x1f, 0), WW - 1);
        const int y0c = min(max((int)y0f, 0), HH - 1);
        const int y1c = min(max((int)y1f, 0), HH - 1);

        const int q0 = x0c & ~3;   // x0 quad column
        const int q1 = x1c & ~3;   // x1 quad column
        cand[tid * 4 + 0] = (y0c << 8) + q0;
        cand[tid * 4 + 1] = (y0c << 8) + q1;
        cand[tid * 4 + 2] = (y1c << 8) + q0;
        cand[tid * 4 + 3] = (y1c << 8) + q1;

        float4 w;
        w.x = (vx0 && vy0) ? wx0 * wy0 : 0.0f;
        w.y = (vx1 && vy0) ? wx1 * wy0 : 0.0f;
        w.z = (vx0 && vy1) ? wx0 * wy1 : 0.0f;
        w.w = (vx1 && vy1) ? wx1 * wy1 : 0.0f;
        g_wts[(size_t)r * NPTS + tid] = w;
        g_apk[(size_t)r * NPTS + tid] = (x0c & 3) | ((x1c & 3) << 2);
    }
    __syncthreads();

    // Leader scan: first index with equal candidate value (broadcast reads).
    if (tid < NCAND) {
        const int c = cand[tid];
        int ld = tid;
        for (int j = 0; j < NCAND; ++j) {
            const int cj = cand[j];
            if (j < tid && cj == c && ld == tid) ld = j;
        }
        lead[tid] = ld;
        flag[tid] = (ld == tid) ? 1 : 0;
    }
    __syncthreads();

    // Exclusive prefix of flags (broadcast reads), emit unique list.
    if (tid < NCAND) {
        int s = 0;
        for (int j = 0; j < NCAND; ++j) {
            const int f = flag[j];
            if (j < tid) s += f;
        }
        pre[tid] = s;
        if (flag[tid]) g_uoff[(size_t)r * NCAND + s] = cand[tid];
    }
    __syncthreads();

    if (tid < NPTS) {
        short4 sl;
        sl.x = (short)pre[lead[tid * 4 + 0]];
        sl.y = (short)pre[lead[tid * 4 + 1]];
        sl.z = (short)pre[lead[tid * 4 + 2]];
        sl.w = (short)pre[lead[tid * 4 + 3]];
        g_slots[(size_t)r * NPTS + tid] = sl;
    }
    if (tid == 0) g_nu[r] = pre[NCAND - 1] + flag[NCAND - 1];
}

// ---------------------------------------------------------------------------
// Kernel G: gather. Block = (roi, 32-channel group). Per channel: fetch the
// roi's unique quads (<=196 x 16B divergent lane-loads — each load serves
// BOTH x-corners of up to several samples) into LDS, then 49 lanes assemble
// the bilinear samples from LDS. Output staged in LDS, written coalesced.
// ---------------------------------------------------------------------------
__global__ __launch_bounds__(256, 8) void gather_kernel(
    const float* __restrict__ feats,    // (B, C, H, W)
    const float4* __restrict__ g_wts,
    const short4* __restrict__ g_slots,
    const int* __restrict__ g_uoff,
    const int* __restrict__ g_apk,
    const int* __restrict__ g_nu,
    float* __restrict__ out)            // (NROI, C, 7, 7)
{
    __shared__ int    s_uoff[NCAND];
    __shared__ short4 s_slot[NPTS];
    __shared__ int    s_apk[NPTS];
    __shared__ float4 s_wts[NPTS];
    __shared__ float4 s_quad[NCAND];
    __shared__ float  s_out[CG * NPTS];   // 1568

    const int r   = blockIdx.x;
    const int cg  = blockIdx.y;
    const int b   = r >> 6;
    const int tid = threadIdx.x;

    const int nu = g_nu[r];
    if (tid < NCAND && tid < nu) s_uoff[tid] = g_uoff[(size_t)r * NCAND + tid];
    if (tid < NPTS) {
        s_slot[tid] = g_slots[(size_t)r * NPTS + tid];
        s_apk[tid]  = g_apk[(size_t)r * NPTS + tid];
        s_wts[tid]  = g_wts[(size_t)r * NPTS + tid];
    }
    __syncthreads();

    const float* gbase = feats + (((size_t)b * CC + (size_t)cg * CG) << 16);

    for (int cl = 0; cl < CG; ++cl) {
        const float* plane = gbase + ((size_t)cl << 16);
        if (tid < nu) s_quad[tid] = *(const float4*)(plane + s_uoff[tid]);
        __syncthreads();
        if (tid < NPTS) {
            const short4 sl = s_slot[tid];
            const int ap = s_apk[tid];
            const int a0 = ap & 3;
            const int a1 = (ap >> 2) & 3;
            const float4 w = s_wts[tid];
            const float v00 = ((const float*)&s_quad[sl.x])[a0];
            const float v01 = ((const float*)&s_quad[sl.y])[a1];
            const float v10 = ((const float*)&s_quad[sl.z])[a0];
            const float v11 = ((const float*)&s_quad[sl.w])[a1];
            s_out[cl * NPTS + tid] = w.x * v00 + w.y * v01 + w.z * v10 + w.w * v11;
        }
        __syncthreads();
    }

    float* ob = out + (((size_t)r * CC + (size_t)cg * CG) * NPTS);
    for (int j = tid; j < CG * NPTS; j += 256) ob[j] = s_out[j];
}

// ---------------------------------------------------------------------------
// Fallback (R1): used only if workspace is unexpectedly small.
// ---------------------------------------------------------------------------
__global__ __launch_bounds__(256) void fallback_kernel(
    const float* __restrict__ feats,
    const float* __restrict__ rois,
    float* __restrict__ out)
{
    __shared__ int   s_off[4][NPTS];
    __shared__ float s_w[4][NPTS];

    const int r   = blockIdx.x;
    const int cq  = blockIdx.y;
    const int b   = r >> 6;
    const int tid = threadIdx.x;

    if (tid < NPTS) {
        const float cx = rois[r * 5 + 0] * ROI_SCALE;
        const float cy = rois[r * 5 + 1] * ROI_SCALE;
        const float bw = rois[r * 5 + 2] * ROI_SCALE;
        const float bh = rois[r * 5 + 3] * ROI_SCALE;
        const float th = rois[r * 5 + 4];
        const float ct = cosf(th), st = sinf(th);
        const int py = tid / SS;
        const int px = tid - py * SS;
        const float lu = (px + 0.5f) / (float)SS - 0.5f;
        const float lv = (py + 0.5f) / (float)SS - 0.5f;
        const float u = lu * bw, v = lv * bh;
        const float x = cx + u * ct - v * st;
        const float y = cy + u * st + v * ct;
        const float x0f = floorf(x), y0f = floorf(y);
        const float x1f = x0f + 1.0f, y1f = y0f + 1.0f;
        const float wx1 = x - x0f, wx0 = 1.0f - wx1;
        const float wy1 = y - y0f, wy0 = 1.0f - wy1;
        const bool vx0 = (x0f >= 0.0f) && (x0f <= (float)(WW - 1));
        const bool vx1 = (x1f >= 0.0f) && (x1f <= (float)(WW - 1));
        const bool vy0 = (y0f >= 0.0f) && (y0f <= (float)(HH - 1));
        const bool vy1 = (y1f >= 0.0f) && (y1f <= (float)(HH - 1));
        const int x0c = min(max((int)x0f, 0), WW - 1);
        const int x1c = min(max((int)x1f, 0), WW - 1);
        const int y0c = min(max((int)y0f, 0), HH - 1);
        const int y1c = min(max((int)y1f, 0), HH - 1);
        s_off[0][tid] = y0c * WW + x0c;  s_w[0][tid] = (vx0 && vy0) ? wx0 * wy0 : 0.0f;
        s_off[1][tid] = y0c * WW + x1c;  s_w[1][tid] = (vx1 && vy0) ? wx1 * wy0 : 0.0f;
        s_off[2][tid] = y1c * WW + x0c;  s_w[2][tid] = (vx0 && vy1) ? wx0 * wy1 : 0.0f;
        s_off[3][tid] = y1c * WW + x1c;  s_w[3][tid] = (vx1 && vy1) ? wx1 * wy1 : 0.0f;
    }
    __syncthreads();

    const float* plane_base = feats + ((size_t)b * CC + (size_t)cq * 64) * HWV;
    float* ob = out + (size_t)r * CC * NPTS + (size_t)cq * 64 * NPTS;

    #pragma unroll 4
    for (int i = tid; i < 64 * NPTS; i += 256) {
        const int cl = i / NPTS;
        const int p  = i - cl * NPTS;
        const float* plane = plane_base + (size_t)cl * HWV;
        ob[i] = s_w[0][p] * plane[s_off[0][p]] + s_w[1][p] * plane[s_off[1][p]]
              + s_w[2][p] * plane[s_off[2][p]] + s_w[3][p] * plane[s_off[3][p]];
    }
}

extern "C" void kernel_launch(void* const* d_in, const int* in_sizes, int n_in,
                              void* d_out, int out_size, void* d_ws, size_t ws_size,
                              hipStream_t stream) {
    const float* feats = (const float*)d_in[0];
    const float* rois  = (const float*)d_in[1];
    float* out = (float*)d_out;

    if (ws_size < (size_t)WS_NEED) {
        dim3 grid(NROI, 4);
        fallback_kernel<<<grid, 256, 0, stream>>>(feats, rois, out);
        return;
    }

    char* ws = (char*)d_ws;
    float4* g_wts   = (float4*)(ws + WS_WTS_OFF);
    short4* g_slots = (short4*)(ws + WS_SLOT_OFF);
    int*    g_uoff  = (int*)(ws + WS_UOFF_OFF);
    int*    g_apk   = (int*)(ws + WS_APK_OFF);
    int*    g_nu    = (int*)(ws + WS_NU_OFF);

    precompute_kernel<<<NROI, 256, 0, stream>>>(rois, g_wts, g_slots, g_uoff, g_apk, g_nu);

    dim3 g(NROI, NGRP);   // 256 x 8 = 2048 blocks, 8 per CU
    gather_kernel<<<g, 256, 0, stream>>>(feats, g_wts, g_slots, g_uoff, g_apk, g_nu, out);
}